// Round 1
// baseline (580.775 us; speedup 1.0000x reference)
//
#include <hip/hip_runtime.h>

// Problem constants (from reference)
#define B_      4
#define N_ATOMS 100000
#define D_      64
#define F_      8
#define G_      20000
#define A_      3
#define H_      16
#define AD_     (A_ * D_)          // 192
#define BLOCK   128
#define BSTRIDE ((size_t)N_ATOMS * D_)   // floats per batch slice of atoms

// One thread handles one (f, g) clique for ALL B batches (same indices,
// amortizes W1 LDS reads 4x). Block = one f, 128 consecutive g.
__global__ __launch_bounds__(BLOCK)
void cliques_mlp_kernel(const float* __restrict__ atoms,   // [B, N_ATOMS, D]
                        const int*   __restrict__ gi,      // [F,G,A] int32 OR int64 (runtime-detected)
                        const float* __restrict__ W1,      // [F, AD, H]
                        const float* __restrict__ b1,      // [F, H]
                        const float* __restrict__ W2,      // [F, H, 1]
                        const float* __restrict__ b2,      // [F, 1]
                        float* __restrict__ out)           // [B, F*G]
{
    __shared__ float w1s[AD_ * H_];   // 12 KiB
    __shared__ float b1s[H_];
    __shared__ float w2s[H_];
    __shared__ float b2s_s;
    __shared__ int   is64_s;

    const int f   = blockIdx.y;
    const int tid = threadIdx.x;
    const int g   = blockIdx.x * BLOCK + tid;

    // ---- stage per-formula weights into LDS (coalesced float4) ----
    {
        const float4* src = (const float4*)(W1 + (size_t)f * AD_ * H_);
        float4*       dst = (float4*)w1s;
        #pragma unroll
        for (int i = 0; i < (AD_ * H_) / 4; i += BLOCK)
            dst[i + tid] = src[i + tid];
    }
    if (tid < H_) {
        b1s[tid] = b1[f * H_ + tid];
        w2s[tid] = W2[f * H_ + tid];
    }
    if (tid == 0) {
        b2s_s = b2[f];
        // int64-vs-int32 detection: indices < 1e5 fit in the low word; if the
        // buffer is int64, every odd 32-bit word is 0. For int32 data the odds
        // of 32 random indices in [0,1e5) all being 0 is ~1e-160.
        unsigned ored = 0u;
        const unsigned* u = (const unsigned*)gi;
        #pragma unroll
        for (int i = 0; i < 32; ++i) ored |= u[2 * i + 1];
        is64_s = (ored == 0u) ? 1 : 0;
    }
    __syncthreads();

    if (g >= G_) return;

    // ---- load the 3 atom indices for this clique ----
    const long long eidx = ((long long)f * G_ + g) * A_;
    int idx0, idx1, idx2;
    if (is64_s) {
        idx0 = gi[2 * (eidx + 0)];
        idx1 = gi[2 * (eidx + 1)];
        idx2 = gi[2 * (eidx + 2)];
    } else {
        idx0 = gi[eidx + 0];
        idx1 = gi[eidx + 1];
        idx2 = gi[eidx + 2];
    }

    const float* rp[A_] = {
        atoms + (size_t)idx0 * D_,
        atoms + (size_t)idx1 * D_,
        atoms + (size_t)idx2 * D_,
    };

    // ---- accumulators: h[b][16], init with bias ----
    float h[B_][H_];
    #pragma unroll
    for (int b = 0; b < B_; ++b) {
        #pragma unroll
        for (int j = 0; j < H_; ++j) h[b][j] = b1s[j];
    }

    // ---- main loop: 3 atoms x 16 float4 chunks, prefetch next chunk ----
    float4 xn[B_];
    #pragma unroll
    for (int b = 0; b < B_; ++b)
        xn[b] = *(const float4*)(rp[0] + b * BSTRIDE);

    #pragma unroll
    for (int a = 0; a < A_; ++a) {
        #pragma unroll 1
        for (int kc = 0; kc < D_ / 4; ++kc) {
            float4 xc[B_];
            #pragma unroll
            for (int b = 0; b < B_; ++b) xc[b] = xn[b];

            // prefetch next chunk (covered by the 256 FMAs below)
            if (kc < D_ / 4 - 1) {
                #pragma unroll
                for (int b = 0; b < B_; ++b)
                    xn[b] = *(const float4*)(rp[a] + b * BSTRIDE + (size_t)(kc + 1) * 4);
            } else if (a < A_ - 1) {
                #pragma unroll
                for (int b = 0; b < B_; ++b)
                    xn[b] = *(const float4*)(rp[a + 1] + b * BSTRIDE);
            }

            #pragma unroll
            for (int j = 0; j < 4; ++j) {
                // wave-uniform LDS address -> broadcast, conflict-free
                const float4* wv = (const float4*)&w1s[(size_t)(a * D_ + kc * 4 + j) * H_];
                const float4 w0 = wv[0], w1v = wv[1], w2v = wv[2], w3v = wv[3];
                #pragma unroll
                for (int b = 0; b < B_; ++b) {
                    const float xv = (j == 0) ? xc[b].x : (j == 1) ? xc[b].y
                                   : (j == 2) ? xc[b].z : xc[b].w;
                    h[b][0]  = fmaf(xv, w0.x,  h[b][0]);
                    h[b][1]  = fmaf(xv, w0.y,  h[b][1]);
                    h[b][2]  = fmaf(xv, w0.z,  h[b][2]);
                    h[b][3]  = fmaf(xv, w0.w,  h[b][3]);
                    h[b][4]  = fmaf(xv, w1v.x, h[b][4]);
                    h[b][5]  = fmaf(xv, w1v.y, h[b][5]);
                    h[b][6]  = fmaf(xv, w1v.z, h[b][6]);
                    h[b][7]  = fmaf(xv, w1v.w, h[b][7]);
                    h[b][8]  = fmaf(xv, w2v.x, h[b][8]);
                    h[b][9]  = fmaf(xv, w2v.y, h[b][9]);
                    h[b][10] = fmaf(xv, w2v.z, h[b][10]);
                    h[b][11] = fmaf(xv, w2v.w, h[b][11]);
                    h[b][12] = fmaf(xv, w3v.x, h[b][12]);
                    h[b][13] = fmaf(xv, w3v.y, h[b][13]);
                    h[b][14] = fmaf(xv, w3v.z, h[b][14]);
                    h[b][15] = fmaf(xv, w3v.w, h[b][15]);
                }
            }
        }
    }

    // ---- epilogue: sigmoid -> layer 2 -> sigmoid -> store (coalesced) ----
    #pragma unroll
    for (int b = 0; b < B_; ++b) {
        float o = b2s_s;
        #pragma unroll
        for (int j = 0; j < H_; ++j) {
            const float s = 1.0f / (1.0f + __expf(-h[b][j]));
            o = fmaf(s, w2s[j], o);
        }
        o = 1.0f / (1.0f + __expf(-o));
        out[(size_t)b * (F_ * G_) + (size_t)f * G_ + g] = o;
    }
}

extern "C" void kernel_launch(void* const* d_in, const int* in_sizes, int n_in,
                              void* d_out, int out_size, void* d_ws, size_t ws_size,
                              hipStream_t stream) {
    const float* atoms = (const float*)d_in[0];
    const int*   gi    = (const int*)d_in[1];
    const float* W1    = (const float*)d_in[2];
    const float* b1    = (const float*)d_in[3];
    const float* W2    = (const float*)d_in[4];
    const float* b2    = (const float*)d_in[5];
    float*       out   = (float*)d_out;

    dim3 grid((G_ + BLOCK - 1) / BLOCK, F_);
    cliques_mlp_kernel<<<grid, dim3(BLOCK), 0, stream>>>(atoms, gi, W1, b1, W2, b2, out);
}